// Round 2
// baseline (18219.278 us; speedup 1.0000x reference)
//
#include <hip/hip_runtime.h>

#define D_ 512
#define FF_ 1024
#define L_ 4
#define A_ 32
#define B_ 1024
#define STEPS_ 64
#define RB_ 0.0625f   // bf16 rescue band (>100 sigma of bf16 dot error)

#define FMA4(A, S, W) do { (A).x += (S)*(W).x; (A).y += (S)*(W).y; (A).z += (S)*(W).z; (A).w += (S)*(W).w; } while(0)

__device__ __forceinline__ float bflo(unsigned u) { return __uint_as_float(u << 16); }
__device__ __forceinline__ float bfhi(unsigned u) { return __uint_as_float(u & 0xffff0000u); }

// ---------------- one-time precompute: Wvo[l] = Wv[l] @ Wo[l] ----------------
__global__ __launch_bounds__(256) void wvo_kernel(
    const float* __restrict__ Wv, const float* __restrict__ Wo,
    float* __restrict__ Wvo)
{
    __shared__ float wvt[16][D_];
    int bx  = blockIdx.x;
    int l   = bx >> 6;
    int rem = bx & 63;
    int k0  = (rem >> 1) * 16;
    int n   = (rem & 1) * 256 + threadIdx.x;

    const float* wvbase = Wv + (size_t)l * D_ * D_ + (size_t)k0 * D_;
    for (int idx = threadIdx.x; idx < 16 * D_; idx += 256)
        wvt[idx >> 9][idx & (D_ - 1)] = wvbase[idx];
    __syncthreads();

    float acc[16];
#pragma unroll
    for (int kk = 0; kk < 16; ++kk) acc[kk] = 0.f;

    const float* wop = Wo + (size_t)l * D_ * D_ + n;
    for (int m = 0; m < D_; m += 4) {
        float w0 = wop[(m + 0) * D_];
        float w1 = wop[(m + 1) * D_];
        float w2 = wop[(m + 2) * D_];
        float w3 = wop[(m + 3) * D_];
#pragma unroll
        for (int kk = 0; kk < 16; ++kk) {
            float4 wv4 = *(const float4*)&wvt[kk][m];
            acc[kk] += wv4.x * w0 + wv4.y * w1 + wv4.z * w2 + wv4.w * w3;
        }
    }
    float* outp = Wvo + (size_t)l * D_ * D_ + (size_t)k0 * D_ + n;
#pragma unroll
    for (int kk = 0; kk < 16; ++kk) outp[kk * D_] = acc[kk];
}

// ---------------- one-time precompute: bvo[l] = bv[l] @ Wo[l] + bo[l] ----------
__global__ __launch_bounds__(256) void bvo_kernel(
    const float* __restrict__ bv, const float* __restrict__ bo,
    const float* __restrict__ Wo, float* __restrict__ bvo)
{
    int l = blockIdx.x >> 1;
    int n = (blockIdx.x & 1) * 256 + threadIdx.x;
    float acc = bo[l * D_ + n];
    const float* wop = Wo + (size_t)l * D_ * D_ + n;
    const float* bvp = bv + l * D_;
    for (int m = 0; m < D_; ++m) acc += bvp[m] * wop[m * D_];
    bvo[l * D_ + n] = acc;
}

// ---------------- one-time precompute: Wf1 -> bf16 (RNE), same [l][k][n] layout
__global__ __launch_bounds__(256) void wf1bf_kernel(
    const float* __restrict__ Wf1, unsigned short* __restrict__ Wf1bf)
{
    int i = blockIdx.x * 256 + threadIdx.x;   // over 2M/4 float4 groups
    float4 v = ((const float4*)Wf1)[i];
    ushort4 o;
    unsigned u;
    u = __float_as_uint(v.x); o.x = (unsigned short)((u + 0x7fffu + ((u >> 16) & 1u)) >> 16);
    u = __float_as_uint(v.y); o.y = (unsigned short)((u + 0x7fffu + ((u >> 16) & 1u)) >> 16);
    u = __float_as_uint(v.z); o.z = (unsigned short)((u + 0x7fffu + ((u >> 16) & 1u)) >> 16);
    u = __float_as_uint(v.w); o.w = (unsigned short)((u + 0x7fffu + ((u >> 16) & 1u)) >> 16);
    ((ushort4*)Wf1bf)[i] = o;
}

// ---------------- layer norm on 4 LDS rows (256 threads / sample) --------------
__device__ __forceinline__ void layer_norm_lds(
    float (*xb)[D_], float (*hb)[D_],
    const float* __restrict__ g, const float* __restrict__ bt,
    float (*red)[4][2], int sg, int r)
{
    float v0 = xb[sg][r], v1 = xb[sg][r + 256];
    float s  = v0 + v1;
    float ss = v0 * v0 + v1 * v1;
#pragma unroll
    for (int m = 1; m < 64; m <<= 1) {
        s  += __shfl_xor(s, m);
        ss += __shfl_xor(ss, m);
    }
    if ((r & 63) == 0) { red[sg][r >> 6][0] = s; red[sg][r >> 6][1] = ss; }
    __syncthreads();
    float S  = red[sg][0][0] + red[sg][1][0] + red[sg][2][0] + red[sg][3][0];
    float SS = red[sg][0][1] + red[sg][1][1] + red[sg][2][1] + red[sg][3][1];
    float mean = S * (1.f / 512.f);
    float var  = SS * (1.f / 512.f) - mean * mean;
    float rstd = 1.0f / sqrtf(var + 1e-5f);
    hb[sg][r]       = (v0 - mean) * rstd * g[r]       + bt[r];
    hb[sg][r + 256] = (v1 - mean) * rstd * g[r + 256] + bt[r + 256];
    __syncthreads();
}

// ---------------- persistent recurrence kernel: 4 samples per workgroup --------
__global__ __launch_bounds__(1024, 4) void smain(
    const float* __restrict__ init_state,
    const float* __restrict__ acts,
    const float* __restrict__ Wa,  const float* __restrict__ ba,
    const float* __restrict__ ln1g, const float* __restrict__ ln1b,
    const float* __restrict__ ln2g, const float* __restrict__ ln2b,
    const float* __restrict__ Wf1, const float* __restrict__ bf1,
    const float* __restrict__ Wf2, const float* __restrict__ bf2,
    const float* __restrict__ lifth,
    const float* __restrict__ Wr,  const float* __restrict__ br,
    const float* __restrict__ Wvo, const float* __restrict__ bvo,
    const unsigned short* __restrict__ Wf1bf,
    float* __restrict__ out_states, float* __restrict__ out_rewards,
    float* __restrict__ out_final)
{
    __shared__ __align__(16) float xb[4][D_];
    __shared__ __align__(16) float hb[4][D_];
    __shared__ __align__(16) float sb[4][D_];
    __shared__ __align__(16) float psc[4][FF_];
    __shared__ float areg[4][A_];
    __shared__ float red[4][4][2];
    __shared__ float rr[16];
    __shared__ int   fire_cnt, resc_cnt;
    __shared__ int   fire_list[256];
    __shared__ int   rescue_list[64];

    const int tid = threadIdx.x;
    const int sg  = tid >> 8;      // sample within WG (0..3)
    const int r   = tid & 255;
    const int b   = blockIdx.x * 4 + sg;

    sb[sg][r]       = init_state[(size_t)b * D_ + r];
    sb[sg][r + 256] = init_state[(size_t)b * D_ + r + 256];
    __syncthreads();

    for (int t = 0; t < STEPS_; ++t) {
        // ---- stage a[b][t][:] ----
        if (tid < 128) {
            int sg2 = tid >> 5, j = tid & 31;
            areg[sg2][j] = acts[((size_t)(blockIdx.x * 4 + sg2)) * (STEPS_ * A_) + t * A_ + j];
        }
        __syncthreads();

        // ---- x = state + a @ Wa + ba  (float2 columns per thread) ----
        {
            float2 xv;
            xv.x = sb[sg][2 * r]     + ba[2 * r];
            xv.y = sb[sg][2 * r + 1] + ba[2 * r + 1];
#pragma unroll
            for (int j = 0; j < A_; ++j) {
                float av = areg[sg][j];
                float2 w = *(const float2*)(Wa + j * D_ + 2 * r);
                xv.x += av * w.x; xv.y += av * w.y;
            }
            xb[sg][2 * r] = xv.x; xb[sg][2 * r + 1] = xv.y;
        }
        __syncthreads();

        for (int l = 0; l < L_; ++l) {
            // ---- LN1: xb -> hb ----
            layer_norm_lds(xb, hb, ln1g + l * D_, ln1b + l * D_, red, sg, r);

            // ---- GEMV1: xb += hb @ Wvo[l] + bvo[l]; c=4 cols, s=8 k-slices ----
            {
                const int slice = tid >> 7;        // 0..7
                const int g     = tid & 127;       // cols 4g..4g+3
                const int k0    = slice * 64;
                const int n0    = g * 4;
                const float4* __restrict__ Wp =
                    (const float4*)(Wvo + (size_t)l * (D_ * D_) + (size_t)k0 * D_) + g;
                const float* h0p = &hb[0][k0];
                const float* h1p = &hb[1][k0];
                const float* h2p = &hb[2][k0];
                const float* h3p = &hb[3][k0];
                float4 a0 = {0.f,0.f,0.f,0.f}, a1 = a0, a2 = a0, a3 = a0;
#pragma unroll 4
                for (int kc = 0; kc < 16; ++kc) {
                    const float4 q0 = *(const float4*)(h0p + 4 * kc);
                    const float4 q1 = *(const float4*)(h1p + 4 * kc);
                    const float4 q2 = *(const float4*)(h2p + 4 * kc);
                    const float4 q3 = *(const float4*)(h3p + 4 * kc);
                    const float4 w0 = Wp[(4 * kc + 0) * 128];
                    const float4 w1 = Wp[(4 * kc + 1) * 128];
                    const float4 w2 = Wp[(4 * kc + 2) * 128];
                    const float4 w3 = Wp[(4 * kc + 3) * 128];
                    FMA4(a0, q0.x, w0); FMA4(a0, q0.y, w1); FMA4(a0, q0.z, w2); FMA4(a0, q0.w, w3);
                    FMA4(a1, q1.x, w0); FMA4(a1, q1.y, w1); FMA4(a1, q1.z, w2); FMA4(a1, q1.w, w3);
                    FMA4(a2, q2.x, w0); FMA4(a2, q2.y, w1); FMA4(a2, q2.z, w2); FMA4(a2, q2.w, w3);
                    FMA4(a3, q3.x, w0); FMA4(a3, q3.y, w1); FMA4(a3, q3.z, w2); FMA4(a3, q3.w, w3);
                }
                if (slice == 0) {
                    float4 bb = *(const float4*)(bvo + l * D_ + n0);
                    a0.x += bb.x; a0.y += bb.y; a0.z += bb.z; a0.w += bb.w;
                    a1.x += bb.x; a1.y += bb.y; a1.z += bb.z; a1.w += bb.w;
                    a2.x += bb.x; a2.y += bb.y; a2.z += bb.z; a2.w += bb.w;
                    a3.x += bb.x; a3.y += bb.y; a3.z += bb.z; a3.w += bb.w;
                }
                atomicAdd(&xb[0][n0 + 0], a0.x); atomicAdd(&xb[0][n0 + 1], a0.y);
                atomicAdd(&xb[0][n0 + 2], a0.z); atomicAdd(&xb[0][n0 + 3], a0.w);
                atomicAdd(&xb[1][n0 + 0], a1.x); atomicAdd(&xb[1][n0 + 1], a1.y);
                atomicAdd(&xb[1][n0 + 2], a1.z); atomicAdd(&xb[1][n0 + 3], a1.w);
                atomicAdd(&xb[2][n0 + 0], a2.x); atomicAdd(&xb[2][n0 + 1], a2.y);
                atomicAdd(&xb[2][n0 + 2], a2.z); atomicAdd(&xb[2][n0 + 3], a2.w);
                atomicAdd(&xb[3][n0 + 0], a3.x); atomicAdd(&xb[3][n0 + 1], a3.y);
                atomicAdd(&xb[3][n0 + 2], a3.z); atomicAdd(&xb[3][n0 + 3], a3.w);
                __syncthreads();
            }

            // ---- init psc = bf1 - 2, reset counters (ordered by LN2's syncs) ----
            {
                int i = tid >> 8, n4 = (tid & 255) << 2;
                float4 bb = *(const float4*)(bf1 + l * FF_ + n4);
                psc[i][n4 + 0] = bb.x - 2.0f; psc[i][n4 + 1] = bb.y - 2.0f;
                psc[i][n4 + 2] = bb.z - 2.0f; psc[i][n4 + 3] = bb.w - 2.0f;
                if (tid == 0) { fire_cnt = 0; resc_cnt = 0; }
            }

            // ---- LN2: xb -> hb ----
            layer_norm_lds(xb, hb, ln2g + l * D_, ln2b + l * D_, red, sg, r);

            // ---- GEMV2 (bf16): psc += hb @ Wf1bf[l]; c=4 cols, s=4 k-slices ----
            {
                const int slice = tid >> 8;        // 0..3
                const int g     = tid & 255;       // cols 4g..4g+3 of FF
                const int k0    = slice * 128;
                const int n0    = g * 4;
                const uint2* __restrict__ Wp =
                    (const uint2*)(Wf1bf + (size_t)l * (D_ * FF_) + (size_t)k0 * FF_) + g;
                const float* h0p = &hb[0][k0];
                const float* h1p = &hb[1][k0];
                const float* h2p = &hb[2][k0];
                const float* h3p = &hb[3][k0];
                float4 a0 = {0.f,0.f,0.f,0.f}, a1 = a0, a2 = a0, a3 = a0;
#pragma unroll 4
                for (int kc = 0; kc < 32; ++kc) {
                    const float4 q0 = *(const float4*)(h0p + 4 * kc);
                    const float4 q1 = *(const float4*)(h1p + 4 * kc);
                    const float4 q2 = *(const float4*)(h2p + 4 * kc);
                    const float4 q3 = *(const float4*)(h3p + 4 * kc);
                    const uint2 u0 = Wp[(4 * kc + 0) * 256];
                    const uint2 u1 = Wp[(4 * kc + 1) * 256];
                    const uint2 u2 = Wp[(4 * kc + 2) * 256];
                    const uint2 u3 = Wp[(4 * kc + 3) * 256];
                    float4 w0 = { bflo(u0.x), bfhi(u0.x), bflo(u0.y), bfhi(u0.y) };
                    float4 w1 = { bflo(u1.x), bfhi(u1.x), bflo(u1.y), bfhi(u1.y) };
                    float4 w2 = { bflo(u2.x), bfhi(u2.x), bflo(u2.y), bfhi(u2.y) };
                    float4 w3 = { bflo(u3.x), bfhi(u3.x), bflo(u3.y), bfhi(u3.y) };
                    FMA4(a0, q0.x, w0); FMA4(a0, q0.y, w1); FMA4(a0, q0.z, w2); FMA4(a0, q0.w, w3);
                    FMA4(a1, q1.x, w0); FMA4(a1, q1.y, w1); FMA4(a1, q1.z, w2); FMA4(a1, q1.w, w3);
                    FMA4(a2, q2.x, w0); FMA4(a2, q2.y, w1); FMA4(a2, q2.z, w2); FMA4(a2, q2.w, w3);
                    FMA4(a3, q3.x, w0); FMA4(a3, q3.y, w1); FMA4(a3, q3.z, w2); FMA4(a3, q3.w, w3);
                }
                atomicAdd(&psc[0][n0 + 0], a0.x); atomicAdd(&psc[0][n0 + 1], a0.y);
                atomicAdd(&psc[0][n0 + 2], a0.z); atomicAdd(&psc[0][n0 + 3], a0.w);
                atomicAdd(&psc[1][n0 + 0], a1.x); atomicAdd(&psc[1][n0 + 1], a1.y);
                atomicAdd(&psc[1][n0 + 2], a1.z); atomicAdd(&psc[1][n0 + 3], a1.w);
                atomicAdd(&psc[2][n0 + 0], a2.x); atomicAdd(&psc[2][n0 + 1], a2.y);
                atomicAdd(&psc[2][n0 + 2], a2.z); atomicAdd(&psc[2][n0 + 3], a2.w);
                atomicAdd(&psc[3][n0 + 0], a3.x); atomicAdd(&psc[3][n0 + 1], a3.y);
                atomicAdd(&psc[3][n0 + 2], a3.z); atomicAdd(&psc[3][n0 + 3], a3.w);
                __syncthreads();
            }

            // ---- detect fires; near-threshold -> rescue list ----
            {
                int i = tid >> 8, n4 = (tid & 255) << 2;
#pragma unroll
                for (int c = 0; c < 4; ++c) {
                    float pr = psc[i][n4 + c];
                    if (pr > RB_) {
                        int idx = atomicAdd(&fire_cnt, 1);
                        if (idx < 256) fire_list[idx] = (i << 12) | (n4 + c);
                    } else if (pr > -RB_) {
                        int idx = atomicAdd(&resc_cnt, 1);
                        if (idx < 64) rescue_list[idx] = (i << 12) | (n4 + c);
                    }
                }
            }
            __syncthreads();

            // ---- rescue: fp32 recompute of near-threshold units (rare) ----
            {
                int rc = resc_cnt; if (rc > 64) rc = 64;
                for (int e = 0; e < rc; ++e) {
                    int ent = rescue_list[e];
                    int i = ent >> 12, n = ent & 4095;
                    float p = 0.f;
                    if (tid < D_)
                        p = hb[i][tid] * Wf1[(size_t)l * (D_ * FF_) + (size_t)tid * FF_ + n];
#pragma unroll
                    for (int m = 1; m < 64; m <<= 1) p += __shfl_xor(p, m);
                    if ((tid & 63) == 0) rr[tid >> 6] = p;
                    __syncthreads();
                    if (tid == 0) {
                        float dot = 0.f;
#pragma unroll
                        for (int w = 0; w < 8; ++w) dot += rr[w];
                        float pre = dot + bf1[l * FF_ + n] - 2.0f;
                        if (pre > 0.f) {
                            int idx = atomicAdd(&fire_cnt, 1);
                            if (idx < 256) fire_list[idx] = ent;
                        }
                    }
                    __syncthreads();
                }
            }

            // ---- sparse s @ Wf2 (rare events) + bf2 ----
            {
                int cnt = fire_cnt; if (cnt > 256) cnt = 256;
                if (cnt > 0) {
                    for (int e = 0; e < cnt; ++e) {
                        int ent = fire_list[e];
                        int i = ent >> 12, n = ent & 4095;
                        if (tid < D_) xb[i][tid] += Wf2[(size_t)l * (FF_ * D_) + (size_t)n * D_ + tid];
                    }
                    __syncthreads();
                }
                xb[sg][r]       += bf2[l * D_ + r];
                xb[sg][r + 256] += bf2[l * D_ + r + 256];
            }
            __syncthreads();
        } // layers

        // ---- LIF spike, outputs, reward ----
        {
            float x0 = xb[sg][r], x1 = xb[sg][r + 256];
            float s0 = (x0 > lifth[r])       ? 1.0f : 0.0f;
            float s1 = (x1 > lifth[r + 256]) ? 1.0f : 0.0f;
            sb[sg][r] = s0; sb[sg][r + 256] = s1;
            size_t so = ((size_t)b * STEPS_ + t) * D_;
            out_states[so + r]       = s0;
            out_states[so + r + 256] = s1;

            float rs = s0 * Wr[r] + s1 * Wr[r + 256];
#pragma unroll
            for (int m = 1; m < 64; m <<= 1) rs += __shfl_xor(rs, m);
            if ((r & 63) == 0) red[sg][r >> 6][0] = rs;
            __syncthreads();
            if (r == 0)
                out_rewards[(size_t)b * STEPS_ + t] =
                    red[sg][0][0] + red[sg][1][0] + red[sg][2][0] + red[sg][3][0] + br[0];
        }
        __syncthreads();
    } // steps

    out_final[(size_t)b * D_ + r]       = sb[sg][r];
    out_final[(size_t)b * D_ + r + 256] = sb[sg][r + 256];
}

extern "C" void kernel_launch(void* const* d_in, const int* in_sizes, int n_in,
                              void* d_out, int out_size, void* d_ws, size_t ws_size,
                              hipStream_t stream) {
    (void)in_sizes; (void)n_in; (void)out_size; (void)ws_size;
    const float* init_state = (const float*)d_in[0];
    const float* acts  = (const float*)d_in[1];
    const float* Wa    = (const float*)d_in[2];
    const float* ba    = (const float*)d_in[3];
    const float* ln1g  = (const float*)d_in[4];
    const float* ln1b  = (const float*)d_in[5];
    // d_in[6..9] = Wq, bq, Wk, bk: dead (softmax over length-1 axis == 1)
    const float* Wv    = (const float*)d_in[10];
    const float* bv    = (const float*)d_in[11];
    const float* Wo    = (const float*)d_in[12];
    const float* bo    = (const float*)d_in[13];
    const float* ln2g  = (const float*)d_in[14];
    const float* ln2b  = (const float*)d_in[15];
    const float* Wf1   = (const float*)d_in[16];
    const float* bf1   = (const float*)d_in[17];
    const float* Wf2   = (const float*)d_in[18];
    const float* bf2   = (const float*)d_in[19];
    const float* lifth = (const float*)d_in[20];
    const float* Wr    = (const float*)d_in[21];
    const float* br    = (const float*)d_in[22];

    float* ws  = (float*)d_ws;
    float* Wvo = ws;                                   // 4*512*512 floats (4MB)
    float* bvo = ws + (size_t)L_ * D_ * D_;            // 2048 floats (8KB)
    unsigned short* Wf1bf = (unsigned short*)(ws + (size_t)L_ * D_ * D_ + L_ * D_); // 2M ushorts (4MB)

    float* out         = (float*)d_out;
    float* out_states  = out;
    float* out_rewards = out + (size_t)B_ * STEPS_ * D_;
    float* out_final   = out_rewards + (size_t)B_ * STEPS_;

    wvo_kernel<<<dim3(256), dim3(256), 0, stream>>>(Wv, Wo, Wvo);
    bvo_kernel<<<dim3(8),   dim3(256), 0, stream>>>(bv, bo, Wo, bvo);
    wf1bf_kernel<<<dim3(2048), dim3(256), 0, stream>>>(Wf1, Wf1bf);
    smain<<<dim3(256), dim3(1024), 0, stream>>>(
        init_state, acts, Wa, ba, ln1g, ln1b, ln2g, ln2b,
        Wf1, bf1, Wf2, bf2, lifth, Wr, br, Wvo, bvo, Wf1bf,
        out_states, out_rewards, out_final);
}

// Round 3
// 7827.352 us; speedup vs baseline: 2.3276x; 2.3276x over previous
//
#include <hip/hip_runtime.h>

#define D_ 512
#define FF_ 1024
#define L_ 4
#define A_ 32
#define B_ 1024
#define STEPS_ 64
#define RB_ 0.0625f   // rescue band; main-dot err sigma ~1.8e-3 => 34 sigma

typedef __attribute__((ext_vector_type(8))) short bf16x8;
typedef __attribute__((ext_vector_type(4))) float f32x4;
#define MFMA16(a,b,c) __builtin_amdgcn_mfma_f32_16x16x32_bf16(a,b,c,0,0,0)

__device__ __forceinline__ unsigned rne16(float f) {
    unsigned u = __float_as_uint(f);
    return (u + 0x7fffu + ((u >> 16) & 1u)) >> 16;
}
__device__ __forceinline__ float fb(unsigned hu) { return __uint_as_float(hu << 16); }

// ---------------- Wvo[l] = Wv[l] @ Wo[l], emitted as split-bf16 MFMA fragments --
// Fragment layout (16x16x32 bf16 B-operand): frag(l,nt,kk): lane holds
// B[k = kk*32 + (lane>>4)*8 + j][n = nt*16 + (lane&15)], j=0..7 packed 16B/lane.
__global__ __launch_bounds__(256) void wvo_kernel(
    const float* __restrict__ Wv, const float* __restrict__ Wo,
    unsigned* __restrict__ Whi, unsigned* __restrict__ Wlo)
{
    __shared__ float wvt[16][D_];
    int bx  = blockIdx.x;
    int l   = bx >> 6;
    int rem = bx & 63;
    int k0  = (rem >> 1) * 16;         // multiple of 16
    int n   = (rem & 1) * 256 + threadIdx.x;

    const float* wvbase = Wv + (size_t)l * D_ * D_ + (size_t)k0 * D_;
    for (int idx = threadIdx.x; idx < 16 * D_; idx += 256)
        wvt[idx >> 9][idx & (D_ - 1)] = wvbase[idx];
    __syncthreads();

    float acc[16];
#pragma unroll
    for (int kk = 0; kk < 16; ++kk) acc[kk] = 0.f;

    const float* wop = Wo + (size_t)l * D_ * D_ + n;
    for (int m = 0; m < D_; m += 4) {
        float w0 = wop[(m + 0) * D_];
        float w1 = wop[(m + 1) * D_];
        float w2 = wop[(m + 2) * D_];
        float w3 = wop[(m + 3) * D_];
#pragma unroll
        for (int kk = 0; kk < 16; ++kk) {
            float4 wv4 = *(const float4*)&wvt[kk][m];
            acc[kk] += wv4.x * w0 + wv4.y * w1 + wv4.z * w2 + wv4.w * w3;
        }
    }
    // epilogue: split each Wvo value into bf16 hi + bf16 lo, store frag-packed
    int nt = n >> 4, ln15 = n & 15;
    int kkblk = k0 >> 5;
    int gbase = (k0 & 31) >> 3;        // 0 or 2
#pragma unroll
    for (int gi = 0; gi < 2; ++gi) {
        int lane_s = ((gbase + gi) << 4) | ln15;
        size_t fbase = ((((size_t)l * 32 + nt) * 16 + kkblk) * 64 + lane_s) * 4;
#pragma unroll
        for (int jp = 0; jp < 4; ++jp) {
            float v0 = acc[gi * 8 + jp * 2], v1 = acc[gi * 8 + jp * 2 + 1];
            unsigned h0 = rne16(v0), h1 = rne16(v1);
            Whi[fbase + jp] = h0 | (h1 << 16);
            float r0 = v0 - fb(h0), r1 = v1 - fb(h1);
            Wlo[fbase + jp] = rne16(r0) | (rne16(r1) << 16);
        }
    }
}

// ---------------- bvo[l] = bv[l] @ Wo[l] + bo[l] -------------------------------
__global__ __launch_bounds__(256) void bvo_kernel(
    const float* __restrict__ bv, const float* __restrict__ bo,
    const float* __restrict__ Wo, float* __restrict__ bvo)
{
    int l = blockIdx.x >> 1;
    int n = (blockIdx.x & 1) * 256 + threadIdx.x;
    float acc = bo[l * D_ + n];
    const float* wop = Wo + (size_t)l * D_ * D_ + n;
    const float* bvp = bv + l * D_;
    for (int m = 0; m < D_; ++m) acc += bvp[m] * wop[m * D_];
    bvo[l * D_ + n] = acc;
}

// ---------------- Wf1 -> bf16 MFMA fragments (hi only) -------------------------
__global__ __launch_bounds__(64) void packwf1_kernel(
    const float* __restrict__ Wf1, unsigned* __restrict__ Pf)
{
    int bid = blockIdx.x;              // 4*64*16 = 4096
    int lane = threadIdx.x;
    int l  = bid >> 10;
    int nt = (bid >> 4) & 63;
    int kk = bid & 15;
    int krow = kk * 32 + (lane >> 4) * 8;
    int n    = nt * 16 + (lane & 15);
    const float* src = Wf1 + ((size_t)l * D_ + krow) * FF_ + n;
    unsigned o[4];
#pragma unroll
    for (int jp = 0; jp < 4; ++jp) {
        unsigned a = rne16(src[(2 * jp) * FF_]);
        unsigned b = rne16(src[(2 * jp + 1) * FF_]);
        o[jp] = a | (b << 16);
    }
    size_t fbase = (((size_t)(l * 64 + nt) * 16 + kk) * 64 + lane) * 4;
    Pf[fbase + 0] = o[0]; Pf[fbase + 1] = o[1];
    Pf[fbase + 2] = o[2]; Pf[fbase + 3] = o[3];
}

// ---------------- LN: xb -> A-fragments (rows sg: hi, rows sg+4: lo) -----------
__device__ __forceinline__ void layer_norm_frag(
    float (*xb)[D_], unsigned* __restrict__ afrag,
    const float* __restrict__ g, const float* __restrict__ bt,
    float (*red)[4][2], int sg, int r)
{
    int c = 2 * r;
    float v0 = xb[sg][c], v1 = xb[sg][c + 1];
    float s  = v0 + v1;
    float ss = v0 * v0 + v1 * v1;
#pragma unroll
    for (int m = 1; m < 64; m <<= 1) {
        s  += __shfl_xor(s, m);
        ss += __shfl_xor(ss, m);
    }
    if ((r & 63) == 0) { red[sg][r >> 6][0] = s; red[sg][r >> 6][1] = ss; }
    __syncthreads();
    float S  = red[sg][0][0] + red[sg][1][0] + red[sg][2][0] + red[sg][3][0];
    float SS = red[sg][0][1] + red[sg][1][1] + red[sg][2][1] + red[sg][3][1];
    float mean = S * (1.f / 512.f);
    float var  = SS * (1.f / 512.f) - mean * mean;
    float rstd = 1.0f / sqrtf(var + 1e-5f);
    float h0 = (v0 - mean) * rstd * g[c]     + bt[c];
    float h1 = (v1 - mean) * rstd * g[c + 1] + bt[c + 1];
    unsigned u0 = rne16(h0), u1 = rne16(h1);
    float l0 = h0 - fb(u0), l1 = h1 - fb(u1);
    int kk = c >> 5, grp = (c & 31) >> 3, jp = (c & 7) >> 1;
    afrag[(kk * 64 + ((grp << 4) | sg))       * 4 + jp] = u0 | (u1 << 16);
    afrag[(kk * 64 + ((grp << 4) | (sg + 4))) * 4 + jp] = rne16(l0) | (rne16(l1) << 16);
    __syncthreads();
}

// ---------------- persistent recurrence kernel ---------------------------------
__global__ __launch_bounds__(1024) void smain(
    const float* __restrict__ init_state,
    const float* __restrict__ acts,
    const float* __restrict__ Wa,  const float* __restrict__ ba,
    const float* __restrict__ ln1g, const float* __restrict__ ln1b,
    const float* __restrict__ ln2g, const float* __restrict__ ln2b,
    const float* __restrict__ Wf1, const float* __restrict__ bf1,
    const float* __restrict__ Wf2, const float* __restrict__ bf2,
    const float* __restrict__ lifth,
    const float* __restrict__ Wr,  const float* __restrict__ br,
    const unsigned* __restrict__ Whi, const unsigned* __restrict__ Wlo,
    const unsigned* __restrict__ Pf, const float* __restrict__ bvo,
    float* __restrict__ out_states, float* __restrict__ out_rewards,
    float* __restrict__ out_final)
{
    __shared__ __align__(16) unsigned afrag[16 * 64 * 4];  // 16KB A fragments
    __shared__ __align__(16) float xb[4][D_];
    __shared__ __align__(16) float sb[4][D_];
    __shared__ float areg[4][A_];
    __shared__ float red[4][4][2];
    __shared__ float rr[16];
    __shared__ int   fire_cnt, resc_cnt;
    __shared__ int   fire_list[256];
    __shared__ int   rescue_list[64];

    const int tid  = threadIdx.x;
    const int sg   = tid >> 8;
    const int r    = tid & 255;
    const int wv   = tid >> 6;     // wave 0..15
    const int lane = tid & 63;
    const int b    = blockIdx.x * 4 + sg;

    sb[sg][r]       = init_state[(size_t)b * D_ + r];
    sb[sg][r + 256] = init_state[(size_t)b * D_ + r + 256];
    // zero A-frag once: rows 8..15 (lane&15 >= 8) stay zero forever
#pragma unroll
    for (int z = 0; z < 4; ++z) afrag[tid + z * 1024] = 0;
    __syncthreads();

    for (int t = 0; t < STEPS_; ++t) {
        if (tid < 128) {
            int sg2 = tid >> 5, j = tid & 31;
            areg[sg2][j] = acts[((size_t)(blockIdx.x * 4 + sg2)) * (STEPS_ * A_) + t * A_ + j];
        }
        __syncthreads();

        // ---- x = state + a @ Wa + ba ----
        {
            float2 xv;
            xv.x = sb[sg][2 * r]     + ba[2 * r];
            xv.y = sb[sg][2 * r + 1] + ba[2 * r + 1];
#pragma unroll
            for (int j = 0; j < A_; ++j) {
                float av = areg[sg][j];
                float2 w = *(const float2*)(Wa + j * D_ + 2 * r);
                xv.x += av * w.x; xv.y += av * w.y;
            }
            xb[sg][2 * r] = xv.x; xb[sg][2 * r + 1] = xv.y;
        }
        __syncthreads();

        for (int l = 0; l < L_; ++l) {
            // ---- LN1: xb -> afrag (h1 hi rows 0-3, lo rows 4-7) ----
            layer_norm_frag(xb, afrag, ln1g + l * D_, ln1b + l * D_, red, sg, r);

            // ---- GEMM1 (MFMA): xb += (hhi+hlo) @ (Whi+Wlo) + bvo ----
            {
                const bf16x8* Ah = (const bf16x8*)afrag;
                const size_t lb = (size_t)l * 32 * 16 * 64;
                const bf16x8* BH = (const bf16x8*)Whi + lb;
                const bf16x8* BL = (const bf16x8*)Wlo + lb;
                const int nt0 = 2 * wv, nt1 = nt0 + 1;
                f32x4 c1a = {0.f,0.f,0.f,0.f}, c2a = c1a, c1b = c1a, c2b = c1a;
#pragma unroll 4
                for (int kk = 0; kk < 16; ++kk) {
                    bf16x8 a  = Ah[kk * 64 + lane];
                    bf16x8 h0 = BH[(nt0 * 16 + kk) * 64 + lane];
                    bf16x8 g0 = BL[(nt0 * 16 + kk) * 64 + lane];
                    bf16x8 h1 = BH[(nt1 * 16 + kk) * 64 + lane];
                    bf16x8 g1 = BL[(nt1 * 16 + kk) * 64 + lane];
                    c1a = MFMA16(a, h0, c1a); c2a = MFMA16(a, g0, c2a);
                    c1b = MFMA16(a, h1, c1b); c2b = MFMA16(a, g1, c2b);
                }
                // combine: row s (hhi@W) + row s+4 (hlo@W); C-layout:
                // col=lane&15, row=(lane>>4)*4+reg  [m89-verified]
#pragma unroll
                for (int s = 0; s < 4; ++s) {
                    float pa = c1a[s] + c2a[s]; float qa = __shfl(pa, (lane & 15) + 16);
                    float pb = c1b[s] + c2b[s]; float qb = __shfl(pb, (lane & 15) + 16);
                    if (lane < 16) {
                        int ca = nt0 * 16 + lane, cb = nt1 * 16 + lane;
                        xb[s][ca] += pa + qa + bvo[l * D_ + ca];
                        xb[s][cb] += pb + qb + bvo[l * D_ + cb];
                    }
                }
            }
            __syncthreads();

            if (tid == 0) { fire_cnt = 0; resc_cnt = 0; }

            // ---- LN2: xb -> afrag (h2 hi/lo) ----
            layer_norm_frag(xb, afrag, ln2g + l * D_, ln2b + l * D_, red, sg, r);

            // ---- GEMM2 (MFMA): pre = (h2hi+h2lo) @ Wf1bf + bf1 - 2; detect ----
            {
                const bf16x8* Ah = (const bf16x8*)afrag;
                const bf16x8* PB = (const bf16x8*)Pf + (size_t)l * 64 * 16 * 64;
                const int m0 = 4 * wv;
                f32x4 p0 = {0.f,0.f,0.f,0.f}, p1 = p0, p2 = p0, p3 = p0;
#pragma unroll 4
                for (int kk = 0; kk < 16; ++kk) {
                    bf16x8 a  = Ah[kk * 64 + lane];
                    bf16x8 b0 = PB[((m0 + 0) * 16 + kk) * 64 + lane];
                    bf16x8 b1 = PB[((m0 + 1) * 16 + kk) * 64 + lane];
                    bf16x8 b2 = PB[((m0 + 2) * 16 + kk) * 64 + lane];
                    bf16x8 b3 = PB[((m0 + 3) * 16 + kk) * 64 + lane];
                    p0 = MFMA16(a, b0, p0); p1 = MFMA16(a, b1, p1);
                    p2 = MFMA16(a, b2, p2); p3 = MFMA16(a, b3, p3);
                }
                const float* bf1g = bf1 + l * FF_;
#pragma unroll
                for (int s = 0; s < 4; ++s) {
                    float v0 = p0[s]; float w0 = __shfl(v0, (lane & 15) + 16);
                    float v1 = p1[s]; float w1 = __shfl(v1, (lane & 15) + 16);
                    float v2 = p2[s]; float w2 = __shfl(v2, (lane & 15) + 16);
                    float v3 = p3[s]; float w3 = __shfl(v3, (lane & 15) + 16);
                    if (lane < 16) {
#pragma unroll
                        for (int q = 0; q < 4; ++q) {
                            float sum = (q == 0) ? v0 + w0 : (q == 1) ? v1 + w1
                                       : (q == 2) ? v2 + w2 : v3 + w3;
                            int n = (m0 + q) * 16 + lane;
                            float pr = sum + bf1g[n] - 2.0f;
                            if (pr > RB_) {
                                int idx = atomicAdd(&fire_cnt, 1);
                                if (idx < 256) fire_list[idx] = (s << 12) | n;
                            } else if (pr > -RB_) {
                                int idx = atomicAdd(&resc_cnt, 1);
                                if (idx < 64) rescue_list[idx] = (s << 12) | n;
                            }
                        }
                    }
                }
            }
            __syncthreads();

            // ---- rescue: near-fp32 recompute (h2 = hi+lo) of near-threshold ----
            {
                int rc = resc_cnt; if (rc > 64) rc = 64;
                for (int e = 0; e < rc; ++e) {
                    int ent = rescue_list[e];
                    int i = ent >> 12, n = ent & 4095;
                    float p = 0.f;
                    if (tid < D_) {
                        int k = tid;
                        int kk = k >> 5, grp = (k & 31) >> 3, jp = (k & 7) >> 1;
                        unsigned whi = afrag[(kk * 64 + ((grp << 4) | i))       * 4 + jp];
                        unsigned wlo = afrag[(kk * 64 + ((grp << 4) | (i + 4))) * 4 + jp];
                        unsigned sh = (k & 1) ? 16 : 0;
                        float h = fb((whi >> sh) & 0xffffu) + fb((wlo >> sh) & 0xffffu);
                        p = h * Wf1[((size_t)l * D_ + k) * FF_ + n];
                    }
#pragma unroll
                    for (int m = 1; m < 64; m <<= 1) p += __shfl_xor(p, m);
                    if ((tid & 63) == 0) rr[tid >> 6] = p;
                    __syncthreads();
                    if (tid == 0) {
                        float dot = 0.f;
#pragma unroll
                        for (int w = 0; w < 8; ++w) dot += rr[w];
                        float pre = dot + bf1[l * FF_ + n] - 2.0f;
                        if (pre > 0.f) {
                            int idx = atomicAdd(&fire_cnt, 1);
                            if (idx < 256) fire_list[idx] = ent;
                        }
                    }
                    __syncthreads();
                }
            }

            // ---- sparse s @ Wf2 + bf2 ----
            {
                int cnt = fire_cnt; if (cnt > 256) cnt = 256;
                if (cnt > 0) {
                    for (int e = 0; e < cnt; ++e) {
                        int ent = fire_list[e];
                        int i = ent >> 12, n = ent & 4095;
                        if (tid < D_) xb[i][tid] += Wf2[(size_t)l * (FF_ * D_) + (size_t)n * D_ + tid];
                    }
                    __syncthreads();
                }
                xb[sg][r]       += bf2[l * D_ + r];
                xb[sg][r + 256] += bf2[l * D_ + r + 256];
            }
            __syncthreads();
        } // layers

        // ---- LIF spike, outputs, reward ----
        {
            float x0 = xb[sg][r], x1 = xb[sg][r + 256];
            float s0 = (x0 > lifth[r])       ? 1.0f : 0.0f;
            float s1 = (x1 > lifth[r + 256]) ? 1.0f : 0.0f;
            sb[sg][r] = s0; sb[sg][r + 256] = s1;
            size_t so = ((size_t)b * STEPS_ + t) * D_;
            out_states[so + r]       = s0;
            out_states[so + r + 256] = s1;

            float rs = s0 * Wr[r] + s1 * Wr[r + 256];
#pragma unroll
            for (int m = 1; m < 64; m <<= 1) rs += __shfl_xor(rs, m);
            if ((r & 63) == 0) red[sg][r >> 6][0] = rs;
            __syncthreads();
            if (r == 0)
                out_rewards[(size_t)b * STEPS_ + t] =
                    red[sg][0][0] + red[sg][1][0] + red[sg][2][0] + red[sg][3][0] + br[0];
        }
        __syncthreads();
    } // steps

    out_final[(size_t)b * D_ + r]       = sb[sg][r];
    out_final[(size_t)b * D_ + r + 256] = sb[sg][r + 256];
}

extern "C" void kernel_launch(void* const* d_in, const int* in_sizes, int n_in,
                              void* d_out, int out_size, void* d_ws, size_t ws_size,
                              hipStream_t stream) {
    (void)in_sizes; (void)n_in; (void)out_size; (void)ws_size;
    const float* init_state = (const float*)d_in[0];
    const float* acts  = (const float*)d_in[1];
    const float* Wa    = (const float*)d_in[2];
    const float* ba    = (const float*)d_in[3];
    const float* ln1g  = (const float*)d_in[4];
    const float* ln1b  = (const float*)d_in[5];
    // d_in[6..9] = Wq, bq, Wk, bk: dead (softmax over length-1 axis == 1)
    const float* Wv    = (const float*)d_in[10];
    const float* bv    = (const float*)d_in[11];
    const float* Wo    = (const float*)d_in[12];
    const float* bo    = (const float*)d_in[13];
    const float* ln2g  = (const float*)d_in[14];
    const float* ln2b  = (const float*)d_in[15];
    const float* Wf1   = (const float*)d_in[16];
    const float* bf1   = (const float*)d_in[17];
    const float* Wf2   = (const float*)d_in[18];
    const float* bf2   = (const float*)d_in[19];
    const float* lifth = (const float*)d_in[20];
    const float* Wr    = (const float*)d_in[21];
    const float* br    = (const float*)d_in[22];

    // ws: Whi(2MB) | Wlo(2MB) | Pf(4MB) | bvo(8KB)   -- total ~8.01MB
    unsigned* Whi = (unsigned*)d_ws;
    unsigned* Wlo = Whi + 524288;
    unsigned* Pf  = Wlo + 524288;
    float*    bvo = (float*)(Pf + 1048576);

    float* out         = (float*)d_out;
    float* out_states  = out;
    float* out_rewards = out + (size_t)B_ * STEPS_ * D_;
    float* out_final   = out_rewards + (size_t)B_ * STEPS_;

    wvo_kernel<<<dim3(256), dim3(256), 0, stream>>>(Wv, Wo, Whi, Wlo);
    bvo_kernel<<<dim3(8),   dim3(256), 0, stream>>>(bv, bo, Wo, bvo);
    packwf1_kernel<<<dim3(4096), dim3(64), 0, stream>>>(Wf1, Pf);
    smain<<<dim3(256), dim3(1024), 0, stream>>>(
        init_state, acts, Wa, ba, ln1g, ln1b, ln2g, ln2b,
        Wf1, bf1, Wf2, bf2, lifth, Wr, br, Whi, Wlo, Pf, bvo,
        out_states, out_rewards, out_final);
}